// Round 5
// baseline (755.321 us; speedup 1.0000x reference)
//
#include <hip/hip_runtime.h>
#include <math.h>

#define BB 8
#define CC 512
#define GG 32
#define CPG 16
#define NN 4096
#define EPSV 1e-5f

typedef __attribute__((ext_vector_type(8))) short bf16x8;
typedef __attribute__((ext_vector_type(4))) float f32x4;

#define GLOAD16(gp, lp)                                                \
  __builtin_amdgcn_global_load_lds(                                    \
      (const __attribute__((address_space(1))) void*)(gp),             \
      (__attribute__((address_space(3))) void*)(lp), 16, 0, 0)

template <int N>
__device__ __forceinline__ void vmwait() {
  static_assert(N == 0 || N == 4 || N == 5 || N == 6 || N == 8 || N == 10 ||
                    N == 12 || N == 16 || N == 20,
                "unsupported vmcnt literal");
  if constexpr (N == 0) asm volatile("s_waitcnt vmcnt(0)" ::: "memory");
  else if constexpr (N == 4) asm volatile("s_waitcnt vmcnt(4)" ::: "memory");
  else if constexpr (N == 5) asm volatile("s_waitcnt vmcnt(5)" ::: "memory");
  else if constexpr (N == 6) asm volatile("s_waitcnt vmcnt(6)" ::: "memory");
  else if constexpr (N == 8) asm volatile("s_waitcnt vmcnt(8)" ::: "memory");
  else if constexpr (N == 10) asm volatile("s_waitcnt vmcnt(10)" ::: "memory");
  else if constexpr (N == 12) asm volatile("s_waitcnt vmcnt(12)" ::: "memory");
  else if constexpr (N == 16) asm volatile("s_waitcnt vmcnt(16)" ::: "memory");
  else if constexpr (N == 20) asm volatile("s_waitcnt vmcnt(20)" ::: "memory");
}

__device__ __forceinline__ unsigned short f2bf(float f) {
  union { float f; unsigned u; } v;
  v.f = f;
  unsigned r = v.u + 0x7FFFu + ((v.u >> 16) & 1u);  // RNE
  return (unsigned short)(r >> 16);
}

// ---------------------------------------------------------------------------
// GroupNorm stats. 256 blocks x 1024 threads.
// ---------------------------------------------------------------------------
__global__ __launch_bounds__(1024) void gn_stats(
    const float* __restrict__ x, const float* __restrict__ gamma,
    const float* __restrict__ beta, float* __restrict__ scale,
    float* __restrict__ shift) {
  int bg = blockIdx.x;
  int b = bg / GG, g = bg % GG;
  const float* base = x + ((size_t)b * CC + (size_t)g * CPG) * NN;
  int t = threadIdx.x;
  float s = 0.f, ss = 0.f;
  const float4* b4 = (const float4*)base;
  const int n4 = CPG * NN / 4;
  for (int idx = t; idx < n4; idx += 1024) {
    float4 v = b4[idx];
    s += v.x + v.y + v.z + v.w;
    ss += v.x * v.x + v.y * v.y + v.z * v.z + v.w * v.w;
  }
  __shared__ float ls[1024], lss[1024];
  ls[t] = s; lss[t] = ss;
  __syncthreads();
  for (int o = 512; o > 0; o >>= 1) {
    if (t < o) { ls[t] += ls[t + o]; lss[t] += lss[t + o]; }
    __syncthreads();
  }
  if (t < CPG) {
    const float invn = 1.0f / (float)(CPG * NN);
    float mean = ls[0] * invn;
    float var = lss[0] * invn - mean * mean;
    float rstd = rsqrtf(var + EPSV);
    int c = g * CPG + t;
    float sc = rstd * gamma[c];
    scale[b * CC + c] = sc;
    shift[b * CC + c] = beta[c] - mean * sc;
  }
}

// ---------------------------------------------------------------------------
// All four fp32 [512x512] weights -> bf16 in one launch
// ---------------------------------------------------------------------------
__global__ __launch_bounds__(256) void cvt_bf16_all(
    const float* __restrict__ w0, const float* __restrict__ w1,
    const float* __restrict__ w2, const float* __restrict__ w3,
    unsigned short* __restrict__ d0, unsigned short* __restrict__ d1,
    unsigned short* __restrict__ d2, unsigned short* __restrict__ d3) {
  const float* src;
  unsigned short* dst;
  switch (blockIdx.y) {
    case 0: src = w0; dst = d0; break;
    case 1: src = w1; dst = d1; break;
    case 2: src = w2; dst = d2; break;
    default: src = w3; dst = d3; break;
  }
  int i = blockIdx.x * 256 + threadIdx.x;
  float4 v = ((const float4*)src)[i];
  ushort4 o;
  o.x = f2bf(v.x); o.y = f2bf(v.y); o.z = f2bf(v.z); o.w = f2bf(v.w);
  ((ushort4*)dst)[i] = o;
}

// ---------------------------------------------------------------------------
// GN-apply + transpose, pair-batched over blockIdx.z
// ---------------------------------------------------------------------------
__global__ __launch_bounds__(256) void gn_apply_t(
    const float* __restrict__ xb, const float* __restrict__ scb,
    const float* __restrict__ shb, unsigned short* __restrict__ ht) {
  const int z = blockIdx.z;
  xb += (size_t)z * NN * CC;
  scb += z * CC;
  shb += z * CC;
  ht += (size_t)z * NN * CC;
  int c0 = blockIdx.y * 64;
  int n0 = blockIdx.x * 64;
  __shared__ unsigned short tile[64][65];
  int t = threadIdx.x;
  int tn = t & 63, t4 = t >> 6;
#pragma unroll
  for (int r = 0; r < 16; ++r) {
    int c = r * 4 + t4;
    float sc = scb[c0 + c];
    float sh = shb[c0 + c];
    float v = xb[(size_t)(c0 + c) * NN + n0 + tn];
    tile[c][tn] = f2bf(v * sc + sh);
  }
  __syncthreads();
#pragma unroll
  for (int r = 0; r < 16; ++r) {
    int n = r * 4 + t4;
    ht[(size_t)(n0 + n) * CC + c0 + tn] = tile[tn][n];
  }
}

// ---------------------------------------------------------------------------
// Fused QKV conv, pair-batched, 3-buffer counted-vmcnt pipeline + XCD swizzle
// LPT (loads/wave/tile) = 2 (A) + 3 (B) = 5  -> vmcnt 10/5/0
// ---------------------------------------------------------------------------
__global__ __launch_bounds__(256) void qkv_conv(
    const unsigned short* __restrict__ A, const unsigned short* __restrict__ W0,
    const unsigned short* __restrict__ W1, const unsigned short* __restrict__ W2,
    const float* __restrict__ b0, const float* __restrict__ b1,
    const float* __restrict__ b2, unsigned short* __restrict__ C0,
    unsigned short* __restrict__ C1, unsigned short* __restrict__ vv) {
  int bx = blockIdx.x, by = blockIdx.y, bz = blockIdx.z;
  {
    const int gx = gridDim.x, gy = gridDim.y;
    const int n = gx * gy * gridDim.z;
    int f = (bz * gy + by) * gx + bx;
    int w = (f & 7) * (n >> 3) + (f >> 3);
    bx = w % gx; int rem = w / gx; by = rem % gy; bz = rem / gy;
  }
  const size_t zoff = (size_t)bz * NN * CC;
  A += zoff; C0 += zoff; C1 += zoff; vv += zoff;
  constexpr int HQ = (128 + 3 * 64) * 32;  // elems per buffer
  __shared__ __align__(16) unsigned short smem[3 * HQ];
  const int m0 = by * 128;
  const int n0 = bx * 64;
  const int t = threadIdx.x;
  const int wave = t >> 6, lane = t & 63;
  const int ln15 = lane & 15, quad = lane >> 4;
  const int wm0 = (wave >> 1) * 64;
  const int wn0 = (wave & 1) * 32;
  const int srow = lane >> 2;
  const int scol = (lane & 3) * 8;

  f32x4 acc0[4][2], acc1[4][2], acc2[4][2];
#pragma unroll
  for (int i = 0; i < 4; ++i)
#pragma unroll
    for (int j = 0; j < 2; ++j)
#pragma unroll
      for (int r = 0; r < 4; ++r) {
        acc0[i][j][r] = 0.f; acc1[i][j][r] = 0.f; acc2[i][j][r] = 0.f;
      }

  auto stage = [&](int buf, int k0) {
    unsigned short* Al = smem + buf * HQ;
    unsigned short* B0l = Al + 128 * 32;
    unsigned short* B1l = B0l + 64 * 32;
    unsigned short* B2l = B1l + 64 * 32;
#pragma unroll
    for (int r = wave; r < 8; r += 4)
      GLOAD16(A + (size_t)(m0 + r * 16 + srow) * CC + k0 + scol,
              Al + r * 16 * 32);
    {
      int r = wave;
      GLOAD16(W0 + (size_t)(n0 + r * 16 + srow) * CC + k0 + scol,
              B0l + r * 16 * 32);
      GLOAD16(W1 + (size_t)(n0 + r * 16 + srow) * CC + k0 + scol,
              B1l + r * 16 * 32);
      GLOAD16(W2 + (size_t)(n0 + r * 16 + srow) * CC + k0 + scol,
              B2l + r * 16 * 32);
    }
  };

  const int nt = CC / 32;  // 16
  stage(0, 0);
  stage(1, 32);
  for (int it = 0; it < nt; ++it) {
    if (it + 2 < nt) { stage((it + 2) % 3, (it + 2) * 32); vmwait<10>(); }
    else if (it + 1 < nt) { vmwait<5>(); }
    else { vmwait<0>(); }
    __builtin_amdgcn_sched_barrier(0);
    __builtin_amdgcn_s_barrier();
    asm volatile("" ::: "memory");
    __builtin_amdgcn_s_setprio(1);
    const unsigned short* Al = smem + (it % 3) * HQ;
    const unsigned short* B0l = Al + 128 * 32;
    const unsigned short* B1l = B0l + 64 * 32;
    const unsigned short* B2l = B1l + 64 * 32;
    bf16x8 af[4], bf0[2], bf1[2], bf2[2];
#pragma unroll
    for (int i = 0; i < 4; ++i)
      af[i] = *(const bf16x8*)(Al + (wm0 + i * 16 + ln15) * 32 + quad * 8);
#pragma unroll
    for (int j = 0; j < 2; ++j) {
      bf0[j] = *(const bf16x8*)(B0l + (wn0 + j * 16 + ln15) * 32 + quad * 8);
      bf1[j] = *(const bf16x8*)(B1l + (wn0 + j * 16 + ln15) * 32 + quad * 8);
      bf2[j] = *(const bf16x8*)(B2l + (wn0 + j * 16 + ln15) * 32 + quad * 8);
    }
#pragma unroll
    for (int i = 0; i < 4; ++i)
#pragma unroll
      for (int j = 0; j < 2; ++j) {
        acc0[i][j] = __builtin_amdgcn_mfma_f32_16x16x32_bf16(af[i], bf0[j], acc0[i][j], 0, 0, 0);
        acc1[i][j] = __builtin_amdgcn_mfma_f32_16x16x32_bf16(af[i], bf1[j], acc1[i][j], 0, 0, 0);
        acc2[i][j] = __builtin_amdgcn_mfma_f32_16x16x32_bf16(af[i], bf2[j], acc2[i][j], 0, 0, 0);
      }
    __builtin_amdgcn_s_setprio(0);
    asm volatile("" ::: "memory");
    __builtin_amdgcn_s_barrier();
  }
#pragma unroll
  for (int i = 0; i < 4; ++i)
#pragma unroll
    for (int j = 0; j < 2; ++j) {
      int col = n0 + wn0 + j * 16 + ln15;
      float c0b = b0[col], c1b = b1[col], c2b = b2[col];
      int row0 = m0 + wm0 + i * 16 + quad * 4;
#pragma unroll
      for (int r = 0; r < 4; ++r) {
        size_t off = (size_t)(row0 + r) * CC + col;
        C0[off] = f2bf(acc0[i][j][r] + c0b);
        C1[off] = f2bf(acc1[i][j][r] + c1b);
      }
      ushort4 pk;
      pk.x = f2bf(acc2[i][j][0] + c2b);
      pk.y = f2bf(acc2[i][j][1] + c2b);
      pk.z = f2bf(acc2[i][j][2] + c2b);
      pk.w = f2bf(acc2[i][j][3] + c2b);
      *(ushort4*)(vv + (size_t)col * NN + row0) = pk;
    }
}

// ---------------------------------------------------------------------------
// QK 8-phase 256x256 GEMM (m201-style): S[z] = (Q . K^T) * scale
// ---------------------------------------------------------------------------
#define QK_NIT 4  // K=512 / (2*64)

#define QK_LDA(LB, FIB)                                                      \
  {                                                                          \
    _Pragma("unroll") for (int fi = 0; fi < 4; ++fi)                         \
        _Pragma("unroll") for (int kk = 0; kk < 2; ++kk)                     \
            Af[fi * 2 + kk] = *(const bf16x8*)((LB) + arow +                 \
                                               (FIB + fi) * 2048 + kk * 64 + \
                                               qoff);                        \
  }

#define QK_LDB(LB, FJB, BSET)                                                \
  {                                                                          \
    _Pragma("unroll") for (int fj = 0; fj < 2; ++fj)                         \
        _Pragma("unroll") for (int kk = 0; kk < 2; ++kk)                     \
            BSET[fj * 2 + kk] = *(const bf16x8*)((LB) + brow +               \
                                                 (FJB + fj) * 2048 +         \
                                                 kk * 64 + qoff);            \
  }

#define QK_MMA(FIB, FJB, BSET)                                               \
  {                                                                          \
    _Pragma("unroll") for (int fi = 0; fi < 4; ++fi)                         \
        _Pragma("unroll") for (int fj = 0; fj < 2; ++fj)                     \
            _Pragma("unroll") for (int kk = 0; kk < 2; ++kk)                 \
                acc[FIB + fi][FJB + fj] =                                    \
                    __builtin_amdgcn_mfma_f32_16x16x32_bf16(                 \
                        Af[fi * 2 + kk], BSET[fj * 2 + kk],                  \
                        acc[FIB + fi][FJB + fj], 0, 0, 0);                   \
  }

#define QK_SYNC()                                          \
  __builtin_amdgcn_s_barrier();                            \
  asm volatile("s_waitcnt lgkmcnt(0)" ::: "memory");       \
  __builtin_amdgcn_sched_barrier(0);                       \
  __builtin_amdgcn_s_setprio(1);

#define QK_END()                                           \
  __builtin_amdgcn_s_setprio(0);                           \
  __builtin_amdgcn_s_barrier();

__global__ __launch_bounds__(512, 2) void qk8(
    const unsigned short* __restrict__ Q, const unsigned short* __restrict__ Kt,
    unsigned short* __restrict__ S, float scale) {
  __shared__ __align__(16) char lds[131072];
  int bx = blockIdx.x, by = blockIdx.y, bz = blockIdx.z;
  {  // XCD-aware bijective swizzle (512 blocks, %8==0)
    const int gx = gridDim.x, gy = gridDim.y;
    const int n = gx * gy * gridDim.z;
    int f = (bz * gy + by) * gx + bx;
    int w = (f & 7) * (n >> 3) + (f >> 3);
    bx = w % gx; int rem = w / gx; by = rem % gy; bz = rem / gy;
  }
  const size_t zoff = (size_t)bz * NN * CC;
  Q += zoff; Kt += zoff;
  unsigned short* Sz = S + (size_t)bz * NN * NN;
  const int m0 = by * 256, n0 = bx * 256;
  const int t = threadIdx.x;
  const int lane = t & 63, wave = t >> 6;
  const int ln15 = lane & 15, quad = lane >> 4;
  const int wm = wave >> 2, wn = wave & 3, wnh = wn >> 1;

  const int trow = t >> 3;
  const int tcol = ((t & 7) * 16) ^ (((t >> 5) & 1) << 5);
  const char* Ab = (const char*)Q + (size_t)(m0 + trow) * (CC * 2) + tcol;
  const char* Bb = (const char*)Kt + (size_t)(n0 + trow) * (CC * 2) + tcol;

  auto stage = [&](const char* base, int mat, int half, int kt) {
    char* dst = lds + ((kt & 1) * 65536 + mat * 32768 + half * 16384) + t * 16;
    const char* src = base + (size_t)(half * 128) * (CC * 2) + kt * 128;
    GLOAD16(src, dst);
    GLOAD16(src + (size_t)64 * (CC * 2), dst + 8192);
  };

  const int qoff = (quad * 16) ^ (((ln15 >> 2) & 1) << 5);
  const int arow = ln15 * 128;
  const int brow = ((wn & 1) * 64 + ln15) * 128;
  const char* ldsA0 = lds + wm * 16384;
  const char* ldsB0 = lds + 32768 + wnh * 16384;
  const char* ldsA1 = ldsA0 + 65536;
  const char* ldsB1 = ldsB0 + 65536;

  f32x4 acc[8][4];
#pragma unroll
  for (int i = 0; i < 8; ++i)
#pragma unroll
    for (int j = 0; j < 4; ++j) {
      acc[i][j][0] = 0.f; acc[i][j][1] = 0.f;
      acc[i][j][2] = 0.f; acc[i][j][3] = 0.f;
    }
  bf16x8 Af[8], B01[4], B23[4];

  stage(Bb, 1, 0, 0); stage(Bb, 1, 1, 0);
  stage(Ab, 0, 0, 0); stage(Ab, 0, 1, 0);
  stage(Bb, 1, 0, 1); stage(Bb, 1, 1, 1);
  asm volatile("s_waitcnt vmcnt(4)" ::: "memory");
  __builtin_amdgcn_sched_barrier(0);
  __builtin_amdgcn_s_barrier();

  for (int it = 0; it < QK_NIT; ++it) {
    const bool nlast = (it != QK_NIT - 1);
    const int t1 = 2 * it + 1, t2 = 2 * it + 2, t3 = 2 * it + 3;
    QK_LDA(ldsA0, 0); QK_LDB(ldsB0, 0, B01);
    stage(Ab, 0, 0, t1);
    QK_SYNC(); QK_MMA(0, 0, B01); QK_END();
    QK_LDB(ldsB0, 2, B23);
    stage(Ab, 0, 1, t1);
    QK_SYNC(); QK_MMA(0, 2, B23); QK_END();
    QK_LDA(ldsA0, 4);
    if (nlast) stage(Bb, 1, 0, t2);
    QK_SYNC(); QK_MMA(4, 0, B01); QK_END();
    if (nlast) stage(Bb, 1, 1, t2);
    QK_SYNC(); QK_MMA(4, 2, B23);
    __builtin_amdgcn_s_setprio(0);
    if (nlast) { asm volatile("s_waitcnt vmcnt(4)" ::: "memory"); }
    else       { asm volatile("s_waitcnt vmcnt(0)" ::: "memory"); }
    __builtin_amdgcn_sched_barrier(0);
    __builtin_amdgcn_s_barrier();
    QK_LDA(ldsA1, 0); QK_LDB(ldsB1, 0, B01);
    if (nlast) stage(Ab, 0, 0, t2);
    QK_SYNC(); QK_MMA(0, 0, B01); QK_END();
    QK_LDB(ldsB1, 2, B23);
    if (nlast) stage(Ab, 0, 1, t2);
    QK_SYNC(); QK_MMA(0, 2, B23); QK_END();
    QK_LDA(ldsA1, 4);
    if (nlast) stage(Bb, 1, 0, t3);
    QK_SYNC(); QK_MMA(4, 0, B01); QK_END();
    if (nlast) stage(Bb, 1, 1, t3);
    QK_SYNC(); QK_MMA(4, 2, B23);
    __builtin_amdgcn_s_setprio(0);
    if (nlast) { asm volatile("s_waitcnt vmcnt(4)" ::: "memory"); }
    __builtin_amdgcn_sched_barrier(0);
    __builtin_amdgcn_s_barrier();
  }

  unsigned short* sm16 = (unsigned short*)lds;
  __syncthreads();
#pragma unroll
  for (int h = 0; h < 2; ++h) {
    if (wm == h) {
#pragma unroll
      for (int fi = 0; fi < 8; ++fi)
#pragma unroll
        for (int fj = 0; fj < 4; ++fj) {
          int lcol = wn * 64 + fj * 16 + ln15;
#pragma unroll
          for (int r = 0; r < 4; ++r) {
            int lrow = fi * 16 + quad * 4 + r;
            sm16[lrow * 272 + lcol] = f2bf(acc[fi][fj][r] * scale);
          }
        }
    }
    __syncthreads();
#pragma unroll
    for (int u = 0; u < 8; ++u) {
      int s = (t + u * 512) * 8;
      int lr = s >> 8, lc = s & 255;
      uint4 d = *(const uint4*)(sm16 + lr * 272 + lc);
      *(uint4*)(Sz + (size_t)(m0 + h * 128 + lr) * NN + n0 + lc) = d;
    }
    __syncthreads();
  }
}

// ---------------------------------------------------------------------------
// Generic TN bf16 MFMA GEMM, batched over blockIdx.z, 3-buffer counted-vmcnt
// pipeline (never drains vmcnt to 0 mid-loop), NC 32-wide K-chunks
// (BK=NC*32), optional XCD swizzle. CSTG: coalesced bf16 epilogue via LDS
// restage (stride BN+16). LPT = NC*(BM/64+BN/64) loads/wave/tile.
// ---------------------------------------------------------------------------
template <int BM, int BN, int NC, int WM, int WN, int WX, int BIAS, bool RESID,
          bool OUTF32, bool CSTG, bool SWZ>
__global__ __launch_bounds__(256) void gemm_tn(
    const unsigned short* __restrict__ A, int lda, size_t sA,
    const unsigned short* __restrict__ B, int ldb, size_t sB,
    void* __restrict__ Cout, int ldc, size_t sC, const float* __restrict__ bias,
    const float* __restrict__ resid, size_t sR, int K, float scale) {
  constexpr int HALF = NC * (BM + BN) * 32;
  constexpr int RPP = (BM < 64) ? BM : 64;
  constexpr int LDW = BN + 16;
  constexpr int CSTG_SH = CSTG ? RPP * LDW : 0;
  constexpr int SMEMN = (3 * HALF > CSTG_SH) ? 3 * HALF : CSTG_SH;
  constexpr int LPT = NC * (BM / 64 + BN / 64);
  __shared__ __align__(16) unsigned short smem[SMEMN];

  int bx = blockIdx.x, by = blockIdx.y, bz = blockIdx.z;
  if (SWZ) {
    const int gx = gridDim.x, gy = gridDim.y;
    const int n = gx * gy * gridDim.z;
    int f = (bz * gy + by) * gx + bx;
    int w = (f & 7) * (n >> 3) + (f >> 3);
    bx = w % gx; int rem = w / gx; by = rem % gy; bz = rem / gy;
  }

  A += (size_t)bz * sA;
  B += (size_t)bz * sB;
  unsigned short* Cb = (unsigned short*)Cout + (size_t)bz * sC;
  float* Cf = (float*)Cout + (size_t)bz * sC;
  if (RESID) resid += (size_t)bz * sR;
  const int m0 = by * BM;
  const int n0 = bx * BN;
  const int t = threadIdx.x;
  const int wave = t >> 6, lane = t & 63;
  const int ln15 = lane & 15, quad = lane >> 4;
  const int wm0 = (wave / WX) * (WM * 16);
  const int wn0 = (wave % WX) * (WN * 16);
  const int srow = lane >> 2;
  const int scol = (lane & 3) * 8;

  const unsigned short* Ag = A + (size_t)(m0 + srow) * lda + scol;
  const unsigned short* Bg = B + (size_t)(n0 + srow) * ldb + scol;

  f32x4 acc[WM][WN];
#pragma unroll
  for (int i = 0; i < WM; ++i)
#pragma unroll
    for (int j = 0; j < WN; ++j) {
      acc[i][j][0] = 0.f; acc[i][j][1] = 0.f;
      acc[i][j][2] = 0.f; acc[i][j][3] = 0.f;
    }

  auto stage = [&](int buf, int k0) {
    unsigned short* Ab = smem + buf * HALF;
    unsigned short* Bb = Ab + NC * BM * 32;
#pragma unroll
    for (int c = 0; c < NC; ++c) {
#pragma unroll
      for (int r = wave; r < BM / 16; r += 4)
        GLOAD16(Ag + (size_t)(r * 16) * lda + k0 + c * 32,
                Ab + (c * BM + r * 16) * 32);
#pragma unroll
      for (int r = wave; r < BN / 16; r += 4)
        GLOAD16(Bg + (size_t)(r * 16) * ldb + k0 + c * 32,
                Bb + (c * BN + r * 16) * 32);
    }
  };

  const int nt = K / (NC * 32);
  stage(0, 0);
  stage(1, NC * 32);
  for (int it = 0; it < nt; ++it) {
    if (it + 2 < nt) { stage((it + 2) % 3, (it + 2) * NC * 32); vmwait<2 * LPT>(); }
    else if (it + 1 < nt) { vmwait<LPT>(); }
    else { vmwait<0>(); }
    __builtin_amdgcn_sched_barrier(0);
    __builtin_amdgcn_s_barrier();
    asm volatile("" ::: "memory");
    __builtin_amdgcn_s_setprio(1);
    const unsigned short* Ab = smem + (it % 3) * HALF;
    const unsigned short* Bb = Ab + NC * BM * 32;
#pragma unroll
    for (int c = 0; c < NC; ++c) {
      bf16x8 af[WM], bfr[WN];
#pragma unroll
      for (int i = 0; i < WM; ++i)
        af[i] = *(const bf16x8*)(Ab + (c * BM + wm0 + i * 16 + ln15) * 32 +
                                 quad * 8);
#pragma unroll
      for (int j = 0; j < WN; ++j)
        bfr[j] = *(const bf16x8*)(Bb + (c * BN + wn0 + j * 16 + ln15) * 32 +
                                  quad * 8);
#pragma unroll
      for (int i = 0; i < WM; ++i)
#pragma unroll
        for (int j = 0; j < WN; ++j)
          acc[i][j] = __builtin_amdgcn_mfma_f32_16x16x32_bf16(af[i], bfr[j],
                                                              acc[i][j], 0, 0, 0);
    }
    __builtin_amdgcn_s_setprio(0);
    asm volatile("" ::: "memory");
    __builtin_amdgcn_s_barrier();
  }

  if (CSTG) {
#pragma unroll
    for (int h = 0; h < BM / RPP; ++h) {
      if (wm0 / RPP == h) {
#pragma unroll
        for (int i = 0; i < WM; ++i)
#pragma unroll
          for (int j = 0; j < WN; ++j) {
            int lcol = wn0 + j * 16 + ln15;
#pragma unroll
            for (int r = 0; r < 4; ++r) {
              int lrow = (wm0 % RPP) + i * 16 + quad * 4 + r;
              smem[lrow * LDW + lcol] = f2bf(acc[i][j][r] * scale);
            }
          }
      }
      __syncthreads();
#pragma unroll
      for (int u = 0; u < RPP * BN / 8 / 256; ++u) {
        int s = (t + u * 256) * 8;
        int lr = s / BN, lc = s % BN;
        uint4 d = *(const uint4*)(smem + lr * LDW + lc);
        *(uint4*)(Cb + (size_t)(m0 + h * RPP + lr) * ldc + n0 + lc) = d;
      }
      __syncthreads();
    }
    return;
  }

#pragma unroll
  for (int i = 0; i < WM; ++i) {
#pragma unroll
    for (int j = 0; j < WN; ++j) {
      int col = n0 + wn0 + j * 16 + ln15;
      float bcol = (BIAS == 2) ? bias[col] : 0.f;
#pragma unroll
      for (int r = 0; r < 4; ++r) {
        int row = m0 + wm0 + i * 16 + quad * 4 + r;
        float v = acc[i][j][r] * scale;
        if (BIAS == 1) v += bias[row];
        if (BIAS == 2) v += bcol;
        if (RESID) v += resid[(size_t)row * ldc + col];
        if (OUTF32)
          Cf[(size_t)row * ldc + col] = v;
        else
          Cb[(size_t)row * ldc + col] = f2bf(v);
      }
    }
  }
}

// ---------------------------------------------------------------------------
// In-place bf16 row softmax (fp32 math)
// ---------------------------------------------------------------------------
__global__ __launch_bounds__(256) void softmax_bf16(unsigned short* __restrict__ S) {
  int i = blockIdx.x;
  uint4* row4 = (uint4*)(S + (size_t)i * NN);
  int t = threadIdx.x;
  uint4 d[2];
  d[0] = row4[t];
  d[1] = row4[t + 256];
  float f[16];
#pragma unroll
  for (int h = 0; h < 2; ++h) {
    unsigned w[4] = {d[h].x, d[h].y, d[h].z, d[h].w};
#pragma unroll
    for (int q = 0; q < 4; ++q) {
      union { unsigned u; float f; } lo, hi;
      lo.u = w[q] << 16;
      hi.u = w[q] & 0xFFFF0000u;
      f[h * 8 + 2 * q] = lo.f;
      f[h * 8 + 2 * q + 1] = hi.f;
    }
  }
  float m = -1e30f;
#pragma unroll
  for (int e = 0; e < 16; ++e) m = fmaxf(m, f[e]);
  __shared__ float red[256];
  red[t] = m;
  __syncthreads();
  for (int o = 128; o > 0; o >>= 1) {
    if (t < o) red[t] = fmaxf(red[t], red[t + o]);
    __syncthreads();
  }
  m = red[0];
  __syncthreads();
  float s = 0.f;
#pragma unroll
  for (int e = 0; e < 16; ++e) {
    f[e] = __expf(f[e] - m);
    s += f[e];
  }
  red[t] = s;
  __syncthreads();
  for (int o = 128; o > 0; o >>= 1) {
    if (t < o) red[t] += red[t + o];
    __syncthreads();
  }
  float inv = 1.0f / red[0];
#pragma unroll
  for (int h = 0; h < 2; ++h) {
    unsigned w[4];
#pragma unroll
    for (int q = 0; q < 4; ++q) {
      unsigned short b0 = f2bf(f[h * 8 + 2 * q] * inv);
      unsigned short b1 = f2bf(f[h * 8 + 2 * q + 1] * inv);
      w[q] = ((unsigned)b1 << 16) | (unsigned)b0;
    }
    uint4 o4; o4.x = w[0]; o4.y = w[1]; o4.z = w[2]; o4.w = w[3];
    row4[t + h * 256] = o4;
  }
}

// ---------------------------------------------------------------------------
extern "C" void kernel_launch(void* const* d_in, const int* in_sizes, int n_in,
                              void* d_out, int out_size, void* d_ws,
                              size_t ws_size, hipStream_t stream) {
  const float* x = (const float*)d_in[0];
  const float* gamma = (const float*)d_in[1];
  const float* beta = (const float*)d_in[2];
  const float* Wq = (const float*)d_in[3];
  const float* bq = (const float*)d_in[4];
  const float* Wk = (const float*)d_in[5];
  const float* bk = (const float*)d_in[6];
  const float* Wv = (const float*)d_in[7];
  const float* bv = (const float*)d_in[8];
  const float* Wp = (const float*)d_in[9];
  const float* bp = (const float*)d_in[10];
  float* out = (float*)d_out;

  char* p = (char*)d_ws;
  const size_t CN = (size_t)NN * CC;
  const size_t CNB = CN * 2;
  unsigned short* qt = (unsigned short*)p; p += 2 * CNB;
  unsigned short* kt = (unsigned short*)p; p += 2 * CNB;
  unsigned short* vv = (unsigned short*)p; p += 2 * CNB;
  unsigned short* S  = (unsigned short*)p; p += (size_t)2 * NN * NN * 2;
  unsigned short* w16 = (unsigned short*)p; p += (size_t)4 * CC * CC * 2;
  unsigned short* wq16 = w16;
  unsigned short* wk16 = w16 + (size_t)CC * CC;
  unsigned short* wv16 = w16 + (size_t)2 * CC * CC;
  unsigned short* wp16 = w16 + (size_t)3 * CC * CC;
  float* scale = (float*)p; p += BB * CC * 4;
  float* shift = (float*)p;
  unsigned short* ht = S;   // alias: ht pair lives in S head until QK runs
  unsigned short* ot = qt;  // alias: qt dead after QK, ot born at PV

  const float rs = 0.04419417382415922f;  // 1/sqrt(512)

  gn_stats<<<BB * GG, 1024, 0, stream>>>(x, gamma, beta, scale, shift);
  cvt_bf16_all<<<dim3(256, 4), 256, 0, stream>>>(Wq, Wk, Wv, Wp, wq16, wk16,
                                                 wv16, wp16);

  for (int pr = 0; pr < BB / 2; ++pr) {
    const int b0 = pr * 2;
    gn_apply_t<<<dim3(NN / 64, CC / 64, 2), 256, 0, stream>>>(
        x + (size_t)b0 * CN, scale + b0 * CC, shift + b0 * CC, ht);
    qkv_conv<<<dim3(CC / 64, NN / 128, 2), 256, 0, stream>>>(
        ht, wq16, wk16, wv16, bq, bk, bv, qt, kt, vv);
    // S[z] = (qt[z] . kt[z]^T) * rs  -- 8-phase 256^2 kernel
    qk8<<<dim3(NN / 256, NN / 256, 2), 512, 0, stream>>>(qt, kt, S, rs);
    softmax_bf16<<<2 * NN, 256, 0, stream>>>(S);
    // PV: full-K (4096), BK=64 (NC=2), counted-vmcnt pipeline + swizzle
    gemm_tn<64, 128, 2, 2, 4, 2, 0, false, false, true, true>
        <<<dim3(CC / 128, NN / 64, 2), 256, 0, stream>>>(
            S, NN, (size_t)NN * NN, vv, NN, CN, ot, CC, CN, nullptr, nullptr,
            0, NN, 1.0f);
    // proj + bias + residual, fp32 out, BK=64, counted-vmcnt + swizzle
    gemm_tn<64, 64, 2, 2, 2, 2, 1, true, true, false, true>
        <<<dim3(NN / 64, CC / 64, 2), 256, 0, stream>>>(
            wp16, CC, 0, ot, CC, CN, out + (size_t)b0 * CN, NN, CN, bp,
            x + (size_t)b0 * CN, CN, CC, 1.0f);
  }
}

// Round 6
// 723.505 us; speedup vs baseline: 1.0440x; 1.0440x over previous
//
#include <hip/hip_runtime.h>
#include <math.h>

#define BB 8
#define CC 512
#define GG 32
#define CPG 16
#define NN 4096
#define EPSV 1e-5f

typedef __attribute__((ext_vector_type(8))) short bf16x8;
typedef __attribute__((ext_vector_type(4))) float f32x4;

#define GLOAD16(gp, lp)                                                \
  __builtin_amdgcn_global_load_lds(                                    \
      (const __attribute__((address_space(1))) void*)(gp),             \
      (__attribute__((address_space(3))) void*)(lp), 16, 0, 0)

__device__ __forceinline__ unsigned short f2bf(float f) {
  union { float f; unsigned u; } v;
  v.f = f;
  unsigned r = v.u + 0x7FFFu + ((v.u >> 16) & 1u);  // RNE
  return (unsigned short)(r >> 16);
}

// ---------------------------------------------------------------------------
// GroupNorm stats. 256 blocks x 1024 threads.
// ---------------------------------------------------------------------------
__global__ __launch_bounds__(1024) void gn_stats(
    const float* __restrict__ x, const float* __restrict__ gamma,
    const float* __restrict__ beta, float* __restrict__ scale,
    float* __restrict__ shift) {
  int bg = blockIdx.x;
  int b = bg / GG, g = bg % GG;
  const float* base = x + ((size_t)b * CC + (size_t)g * CPG) * NN;
  int t = threadIdx.x;
  float s = 0.f, ss = 0.f;
  const float4* b4 = (const float4*)base;
  const int n4 = CPG * NN / 4;
  for (int idx = t; idx < n4; idx += 1024) {
    float4 v = b4[idx];
    s += v.x + v.y + v.z + v.w;
    ss += v.x * v.x + v.y * v.y + v.z * v.z + v.w * v.w;
  }
  __shared__ float ls[1024], lss[1024];
  ls[t] = s; lss[t] = ss;
  __syncthreads();
  for (int o = 512; o > 0; o >>= 1) {
    if (t < o) { ls[t] += ls[t + o]; lss[t] += lss[t + o]; }
    __syncthreads();
  }
  if (t < CPG) {
    const float invn = 1.0f / (float)(CPG * NN);
    float mean = ls[0] * invn;
    float var = lss[0] * invn - mean * mean;
    float rstd = rsqrtf(var + EPSV);
    int c = g * CPG + t;
    float sc = rstd * gamma[c];
    scale[b * CC + c] = sc;
    shift[b * CC + c] = beta[c] - mean * sc;
  }
}

// ---------------------------------------------------------------------------
// All four fp32 [512x512] weights -> bf16 in one launch
// ---------------------------------------------------------------------------
__global__ __launch_bounds__(256) void cvt_bf16_all(
    const float* __restrict__ w0, const float* __restrict__ w1,
    const float* __restrict__ w2, const float* __restrict__ w3,
    unsigned short* __restrict__ d0, unsigned short* __restrict__ d1,
    unsigned short* __restrict__ d2, unsigned short* __restrict__ d3) {
  const float* src;
  unsigned short* dst;
  switch (blockIdx.y) {
    case 0: src = w0; dst = d0; break;
    case 1: src = w1; dst = d1; break;
    case 2: src = w2; dst = d2; break;
    default: src = w3; dst = d3; break;
  }
  int i = blockIdx.x * 256 + threadIdx.x;
  float4 v = ((const float4*)src)[i];
  ushort4 o;
  o.x = f2bf(v.x); o.y = f2bf(v.y); o.z = f2bf(v.z); o.w = f2bf(v.w);
  ((ushort4*)dst)[i] = o;
}

// ---------------------------------------------------------------------------
// GN-apply + transpose, pair-batched over blockIdx.z
// ---------------------------------------------------------------------------
__global__ __launch_bounds__(256) void gn_apply_t(
    const float* __restrict__ xb, const float* __restrict__ scb,
    const float* __restrict__ shb, unsigned short* __restrict__ ht) {
  const int z = blockIdx.z;
  xb += (size_t)z * NN * CC;
  scb += z * CC;
  shb += z * CC;
  ht += (size_t)z * NN * CC;
  int c0 = blockIdx.y * 64;
  int n0 = blockIdx.x * 64;
  __shared__ unsigned short tile[64][65];
  int t = threadIdx.x;
  int tn = t & 63, t4 = t >> 6;
#pragma unroll
  for (int r = 0; r < 16; ++r) {
    int c = r * 4 + t4;
    float sc = scb[c0 + c];
    float sh = shb[c0 + c];
    float v = xb[(size_t)(c0 + c) * NN + n0 + tn];
    tile[c][tn] = f2bf(v * sc + sh);
  }
  __syncthreads();
#pragma unroll
  for (int r = 0; r < 16; ++r) {
    int n = r * 4 + t4;
    ht[(size_t)(n0 + n) * CC + c0 + tn] = tile[tn][n];
  }
}

// ---------------------------------------------------------------------------
// Fused QKV conv, pair-batched, 2-phase dbuf prefetch + XCD swizzle (R4 form)
// ---------------------------------------------------------------------------
__global__ __launch_bounds__(256) void qkv_conv(
    const unsigned short* __restrict__ A, const unsigned short* __restrict__ W0,
    const unsigned short* __restrict__ W1, const unsigned short* __restrict__ W2,
    const float* __restrict__ b0, const float* __restrict__ b1,
    const float* __restrict__ b2, unsigned short* __restrict__ C0,
    unsigned short* __restrict__ C1, unsigned short* __restrict__ vv) {
  int bx = blockIdx.x, by = blockIdx.y, bz = blockIdx.z;
  {
    const int gx = gridDim.x, gy = gridDim.y;
    const int n = gx * gy * gridDim.z;
    int f = (bz * gy + by) * gx + bx;
    int w = (f & 7) * (n >> 3) + (f >> 3);
    bx = w % gx; int rem = w / gx; by = rem % gy; bz = rem / gy;
  }
  const size_t zoff = (size_t)bz * NN * CC;
  A += zoff; C0 += zoff; C1 += zoff; vv += zoff;
  constexpr int HQ = (128 + 3 * 64) * 32;
  __shared__ __align__(16) unsigned short smem[2 * HQ];
  const int m0 = by * 128;
  const int n0 = bx * 64;
  const int t = threadIdx.x;
  const int wave = t >> 6, lane = t & 63;
  const int ln15 = lane & 15, quad = lane >> 4;
  const int wm0 = (wave >> 1) * 64;
  const int wn0 = (wave & 1) * 32;
  const int srow = lane >> 2;
  const int scol = (lane & 3) * 8;

  f32x4 acc0[4][2], acc1[4][2], acc2[4][2];
#pragma unroll
  for (int i = 0; i < 4; ++i)
#pragma unroll
    for (int j = 0; j < 2; ++j)
#pragma unroll
      for (int r = 0; r < 4; ++r) {
        acc0[i][j][r] = 0.f; acc1[i][j][r] = 0.f; acc2[i][j][r] = 0.f;
      }

  auto stage = [&](int buf, int k0) {
    unsigned short* Al = smem + buf * HQ;
    unsigned short* B0l = Al + 128 * 32;
    unsigned short* B1l = B0l + 64 * 32;
    unsigned short* B2l = B1l + 64 * 32;
#pragma unroll
    for (int r = wave; r < 8; r += 4)
      GLOAD16(A + (size_t)(m0 + r * 16 + srow) * CC + k0 + scol,
              Al + r * 16 * 32);
    {
      int r = wave;
      GLOAD16(W0 + (size_t)(n0 + r * 16 + srow) * CC + k0 + scol,
              B0l + r * 16 * 32);
      GLOAD16(W1 + (size_t)(n0 + r * 16 + srow) * CC + k0 + scol,
              B1l + r * 16 * 32);
      GLOAD16(W2 + (size_t)(n0 + r * 16 + srow) * CC + k0 + scol,
              B2l + r * 16 * 32);
    }
  };

  stage(0, 0);
  __syncthreads();
  for (int it = 0; it < CC / 32; ++it) {
    const int cur = it & 1;
    if (it + 1 < CC / 32) stage(cur ^ 1, (it + 1) * 32);
    const unsigned short* Al = smem + cur * HQ;
    const unsigned short* B0l = Al + 128 * 32;
    const unsigned short* B1l = B0l + 64 * 32;
    const unsigned short* B2l = B1l + 64 * 32;
    bf16x8 af[4], bf0[2], bf1[2], bf2[2];
#pragma unroll
    for (int i = 0; i < 4; ++i)
      af[i] = *(const bf16x8*)(Al + (wm0 + i * 16 + ln15) * 32 + quad * 8);
#pragma unroll
    for (int j = 0; j < 2; ++j) {
      bf0[j] = *(const bf16x8*)(B0l + (wn0 + j * 16 + ln15) * 32 + quad * 8);
      bf1[j] = *(const bf16x8*)(B1l + (wn0 + j * 16 + ln15) * 32 + quad * 8);
      bf2[j] = *(const bf16x8*)(B2l + (wn0 + j * 16 + ln15) * 32 + quad * 8);
    }
#pragma unroll
    for (int i = 0; i < 4; ++i)
#pragma unroll
      for (int j = 0; j < 2; ++j) {
        acc0[i][j] = __builtin_amdgcn_mfma_f32_16x16x32_bf16(af[i], bf0[j], acc0[i][j], 0, 0, 0);
        acc1[i][j] = __builtin_amdgcn_mfma_f32_16x16x32_bf16(af[i], bf1[j], acc1[i][j], 0, 0, 0);
        acc2[i][j] = __builtin_amdgcn_mfma_f32_16x16x32_bf16(af[i], bf2[j], acc2[i][j], 0, 0, 0);
      }
    __syncthreads();
  }
#pragma unroll
  for (int i = 0; i < 4; ++i)
#pragma unroll
    for (int j = 0; j < 2; ++j) {
      int col = n0 + wn0 + j * 16 + ln15;
      float c0b = b0[col], c1b = b1[col], c2b = b2[col];
      int row0 = m0 + wm0 + i * 16 + quad * 4;
#pragma unroll
      for (int r = 0; r < 4; ++r) {
        size_t off = (size_t)(row0 + r) * CC + col;
        C0[off] = f2bf(acc0[i][j][r] + c0b);
        C1[off] = f2bf(acc1[i][j][r] + c1b);
      }
      ushort4 pk;
      pk.x = f2bf(acc2[i][j][0] + c2b);
      pk.y = f2bf(acc2[i][j][1] + c2b);
      pk.z = f2bf(acc2[i][j][2] + c2b);
      pk.w = f2bf(acc2[i][j][3] + c2b);
      *(ushort4*)(vv + (size_t)col * NN + row0) = pk;
    }
}

// ---------------------------------------------------------------------------
// QK 8-phase 256x256 GEMM (m201-style): S[z] = (Q . K^T) * scale
// ---------------------------------------------------------------------------
#define QK_NIT 4  // K=512 / (2*64)

#define QK_LDA(LB, FIB)                                                      \
  {                                                                          \
    _Pragma("unroll") for (int fi = 0; fi < 4; ++fi)                         \
        _Pragma("unroll") for (int kk = 0; kk < 2; ++kk)                     \
            Af[fi * 2 + kk] = *(const bf16x8*)((LB) + arow +                 \
                                               (FIB + fi) * 2048 + kk * 64 + \
                                               qoff);                        \
  }

#define QK_LDB(LB, FJB, BSET)                                                \
  {                                                                          \
    _Pragma("unroll") for (int fj = 0; fj < 2; ++fj)                         \
        _Pragma("unroll") for (int kk = 0; kk < 2; ++kk)                     \
            BSET[fj * 2 + kk] = *(const bf16x8*)((LB) + brow +               \
                                                 (FJB + fj) * 2048 +         \
                                                 kk * 64 + qoff);            \
  }

#define QK_MMA(FIB, FJB, BSET)                                               \
  {                                                                          \
    _Pragma("unroll") for (int fi = 0; fi < 4; ++fi)                         \
        _Pragma("unroll") for (int fj = 0; fj < 2; ++fj)                     \
            _Pragma("unroll") for (int kk = 0; kk < 2; ++kk)                 \
                acc[FIB + fi][FJB + fj] =                                    \
                    __builtin_amdgcn_mfma_f32_16x16x32_bf16(                 \
                        Af[fi * 2 + kk], BSET[fj * 2 + kk],                  \
                        acc[FIB + fi][FJB + fj], 0, 0, 0);                   \
  }

#define QK_SYNC()                                          \
  __builtin_amdgcn_s_barrier();                            \
  asm volatile("s_waitcnt lgkmcnt(0)" ::: "memory");       \
  __builtin_amdgcn_sched_barrier(0);                       \
  __builtin_amdgcn_s_setprio(1);

#define QK_END()                                           \
  __builtin_amdgcn_s_setprio(0);                           \
  __builtin_amdgcn_s_barrier();

__global__ __launch_bounds__(512, 2) void qk8(
    const unsigned short* __restrict__ Q, const unsigned short* __restrict__ Kt,
    unsigned short* __restrict__ S, float scale) {
  __shared__ __align__(16) char lds[131072];
  int bx = blockIdx.x, by = blockIdx.y, bz = blockIdx.z;
  {  // XCD-aware bijective swizzle (512 blocks, %8==0)
    const int gx = gridDim.x, gy = gridDim.y;
    const int n = gx * gy * gridDim.z;
    int f = (bz * gy + by) * gx + bx;
    int w = (f & 7) * (n >> 3) + (f >> 3);
    bx = w % gx; int rem = w / gx; by = rem % gy; bz = rem / gy;
  }
  const size_t zoff = (size_t)bz * NN * CC;
  Q += zoff; Kt += zoff;
  unsigned short* Sz = S + (size_t)bz * NN * NN;
  const int m0 = by * 256, n0 = bx * 256;
  const int t = threadIdx.x;
  const int lane = t & 63, wave = t >> 6;
  const int ln15 = lane & 15, quad = lane >> 4;
  const int wm = wave >> 2, wn = wave & 3, wnh = wn >> 1;

  const int trow = t >> 3;
  const int tcol = ((t & 7) * 16) ^ (((t >> 5) & 1) << 5);
  const char* Ab = (const char*)Q + (size_t)(m0 + trow) * (CC * 2) + tcol;
  const char* Bb = (const char*)Kt + (size_t)(n0 + trow) * (CC * 2) + tcol;

  auto stage = [&](const char* base, int mat, int half, int kt) {
    char* dst = lds + ((kt & 1) * 65536 + mat * 32768 + half * 16384) + t * 16;
    const char* src = base + (size_t)(half * 128) * (CC * 2) + kt * 128;
    GLOAD16(src, dst);
    GLOAD16(src + (size_t)64 * (CC * 2), dst + 8192);
  };

  const int qoff = (quad * 16) ^ (((ln15 >> 2) & 1) << 5);
  const int arow = ln15 * 128;
  const int brow = ((wn & 1) * 64 + ln15) * 128;
  const char* ldsA0 = lds + wm * 16384;
  const char* ldsB0 = lds + 32768 + wnh * 16384;
  const char* ldsA1 = ldsA0 + 65536;
  const char* ldsB1 = ldsB0 + 65536;

  f32x4 acc[8][4];
#pragma unroll
  for (int i = 0; i < 8; ++i)
#pragma unroll
    for (int j = 0; j < 4; ++j) {
      acc[i][j][0] = 0.f; acc[i][j][1] = 0.f;
      acc[i][j][2] = 0.f; acc[i][j][3] = 0.f;
    }
  bf16x8 Af[8], B01[4], B23[4];

  stage(Bb, 1, 0, 0); stage(Bb, 1, 1, 0);
  stage(Ab, 0, 0, 0); stage(Ab, 0, 1, 0);
  stage(Bb, 1, 0, 1); stage(Bb, 1, 1, 1);
  asm volatile("s_waitcnt vmcnt(4)" ::: "memory");
  __builtin_amdgcn_sched_barrier(0);
  __builtin_amdgcn_s_barrier();

  for (int it = 0; it < QK_NIT; ++it) {
    const bool nlast = (it != QK_NIT - 1);
    const int t1 = 2 * it + 1, t2 = 2 * it + 2, t3 = 2 * it + 3;
    QK_LDA(ldsA0, 0); QK_LDB(ldsB0, 0, B01);
    stage(Ab, 0, 0, t1);
    QK_SYNC(); QK_MMA(0, 0, B01); QK_END();
    QK_LDB(ldsB0, 2, B23);
    stage(Ab, 0, 1, t1);
    QK_SYNC(); QK_MMA(0, 2, B23); QK_END();
    QK_LDA(ldsA0, 4);
    if (nlast) stage(Bb, 1, 0, t2);
    QK_SYNC(); QK_MMA(4, 0, B01); QK_END();
    if (nlast) stage(Bb, 1, 1, t2);
    QK_SYNC(); QK_MMA(4, 2, B23);
    __builtin_amdgcn_s_setprio(0);
    if (nlast) { asm volatile("s_waitcnt vmcnt(4)" ::: "memory"); }
    else       { asm volatile("s_waitcnt vmcnt(0)" ::: "memory"); }
    __builtin_amdgcn_sched_barrier(0);
    __builtin_amdgcn_s_barrier();
    QK_LDA(ldsA1, 0); QK_LDB(ldsB1, 0, B01);
    if (nlast) stage(Ab, 0, 0, t2);
    QK_SYNC(); QK_MMA(0, 0, B01); QK_END();
    QK_LDB(ldsB1, 2, B23);
    if (nlast) stage(Ab, 0, 1, t2);
    QK_SYNC(); QK_MMA(0, 2, B23); QK_END();
    QK_LDA(ldsA1, 4);
    if (nlast) stage(Bb, 1, 0, t3);
    QK_SYNC(); QK_MMA(4, 0, B01); QK_END();
    if (nlast) stage(Bb, 1, 1, t3);
    QK_SYNC(); QK_MMA(4, 2, B23);
    __builtin_amdgcn_s_setprio(0);
    if (nlast) { asm volatile("s_waitcnt vmcnt(4)" ::: "memory"); }
    __builtin_amdgcn_sched_barrier(0);
    __builtin_amdgcn_s_barrier();
  }

  unsigned short* sm16 = (unsigned short*)lds;
  __syncthreads();
#pragma unroll
  for (int h = 0; h < 2; ++h) {
    if (wm == h) {
#pragma unroll
      for (int fi = 0; fi < 8; ++fi)
#pragma unroll
        for (int fj = 0; fj < 4; ++fj) {
          int lcol = wn * 64 + fj * 16 + ln15;
#pragma unroll
          for (int r = 0; r < 4; ++r) {
            int lrow = fi * 16 + quad * 4 + r;
            sm16[lrow * 272 + lcol] = f2bf(acc[fi][fj][r] * scale);
          }
        }
    }
    __syncthreads();
#pragma unroll
    for (int u = 0; u < 8; ++u) {
      int s = (t + u * 512) * 8;
      int lr = s >> 8, lc = s & 255;
      uint4 d = *(const uint4*)(sm16 + lr * 272 + lc);
      *(uint4*)(Sz + (size_t)(m0 + h * 128 + lr) * NN + n0 + lc) = d;
    }
    __syncthreads();
  }
}

// ---------------------------------------------------------------------------
// PV 8-phase 128x128 GEMM (qk8 skeleton, 4 waves, wave tile 64x64):
//   ot[i][c] = sum_j S[i][j] * vv[c][j]   (K = 4096, NT = 32)
// Same stage granularity (2 gloads/call), same vmcnt(4) schedule, same
// st_16x32 both-sides swizzle as qk8.
// ---------------------------------------------------------------------------
#define PV_NIT 32

#define PV_LDA(LB, DST, FIB)                                                 \
  {                                                                          \
    _Pragma("unroll") for (int fi = 0; fi < 2; ++fi)                         \
        _Pragma("unroll") for (int kk = 0; kk < 2; ++kk)                     \
            DST[fi * 2 + kk] = *(const bf16x8*)((LB) + aBase +               \
                                                (FIB + fi) * 2048 +          \
                                                kk * 64);                    \
  }

#define PV_LDB(LB, DST, FJB)                                                 \
  {                                                                          \
    _Pragma("unroll") for (int fj = 0; fj < 2; ++fj)                         \
        _Pragma("unroll") for (int kk = 0; kk < 2; ++kk)                     \
            DST[fj * 2 + kk] = *(const bf16x8*)((LB) + bBase +               \
                                                (FJB + fj) * 2048 +          \
                                                kk * 64);                    \
  }

#define PV_MMA(AF, BF, FIB, FJB)                                             \
  {                                                                          \
    _Pragma("unroll") for (int fi = 0; fi < 2; ++fi)                         \
        _Pragma("unroll") for (int fj = 0; fj < 2; ++fj)                     \
            _Pragma("unroll") for (int kk = 0; kk < 2; ++kk)                 \
                acc[FIB + fi][FJB + fj] =                                    \
                    __builtin_amdgcn_mfma_f32_16x16x32_bf16(                 \
                        AF[fi * 2 + kk], BF[fj * 2 + kk],                    \
                        acc[FIB + fi][FJB + fj], 0, 0, 0);                   \
  }

__global__ __launch_bounds__(256, 2) void pv8(
    const unsigned short* __restrict__ Smat, const unsigned short* __restrict__ V,
    unsigned short* __restrict__ O) {
  __shared__ __align__(16) char lds[65536];
  int bx = blockIdx.x, by = blockIdx.y, bz = blockIdx.z;
  {  // XCD-aware bijective swizzle (256 blocks, %8==0)
    const int gx = gridDim.x, gy = gridDim.y;
    const int n = gx * gy * gridDim.z;
    int f = (bz * gy + by) * gx + bx;
    int w = (f & 7) * (n >> 3) + (f >> 3);
    bx = w % gx; int rem = w / gx; by = rem % gy; bz = rem / gy;
  }
  Smat += (size_t)bz * NN * NN;
  V += (size_t)bz * NN * CC;
  unsigned short* Oz = O + (size_t)bz * NN * CC;
  const int m0 = by * 128, n0 = bx * 128;
  const int t = threadIdx.x;
  const int lane = t & 63, wave = t >> 6;
  const int ln15 = lane & 15, quad = lane >> 4;
  const int wm = wave >> 1, wn = wave & 1;

  // staging source (pre-swizzled st_16x32; rows via t>>3, +32 second load)
  const int trow = t >> 3;  // 0..31
  const int tcol = ((t & 7) * 16) ^ (((t >> 5) & 1) << 5);
  const char* Ab = (const char*)Smat + (size_t)(m0 + trow) * (NN * 2) + tcol;
  const char* Bb = (const char*)V + (size_t)(n0 + trow) * (NN * 2) + tcol;

  // LDS: [buf(2)][A|B][128 rows][64 K] bf16; half = 64 rows = 8 KiB
  auto stage = [&](const char* base, int mat, int half, int kt) {
    char* dst = lds + ((kt & 1) * 32768 + mat * 16384 + half * 8192) + t * 16;
    const char* src = base + (size_t)(half * 64) * (NN * 2) + kt * 128;
    GLOAD16(src, dst);
    GLOAD16(src + (size_t)32 * (NN * 2), dst + 4096);
  };

  const int qoff = (quad * 16) ^ (((ln15 >> 2) & 1) << 5);
  const int aBase = wm * 8192 + ln15 * 128 + qoff;
  const int bBase = wn * 8192 + ln15 * 128 + qoff;
  const char* A0 = lds;
  const char* B0 = lds + 16384;
  const char* A1 = lds + 32768;
  const char* B1 = lds + 49152;

  f32x4 acc[4][4];
#pragma unroll
  for (int i = 0; i < 4; ++i)
#pragma unroll
    for (int j = 0; j < 4; ++j) {
      acc[i][j][0] = 0.f; acc[i][j][1] = 0.f;
      acc[i][j][2] = 0.f; acc[i][j][3] = 0.f;
    }
  bf16x8 AfA[4], AfB[4], BfA[4], BfB[4];

  // prologue (qk8 pattern): B(t0), A(t0), B(t1); wait for t0
  stage(Bb, 1, 0, 0); stage(Bb, 1, 1, 0);
  stage(Ab, 0, 0, 0); stage(Ab, 0, 1, 0);
  stage(Bb, 1, 0, 1); stage(Bb, 1, 1, 1);
  asm volatile("s_waitcnt vmcnt(4)" ::: "memory");
  __builtin_amdgcn_sched_barrier(0);
  __builtin_amdgcn_s_barrier();

  for (int it = 0; it < PV_NIT; ++it) {
    const bool nlast = (it != PV_NIT - 1);
    const int t1 = 2 * it + 1, t2 = 2 * it + 2, t3 = 2 * it + 3;
    // ph1
    PV_LDA(A0, AfA, 0); PV_LDB(B0, BfA, 0);
    stage(Ab, 0, 0, t1);
    QK_SYNC(); PV_MMA(AfA, BfA, 0, 0); QK_END();
    // ph2
    PV_LDB(B0, BfB, 2);
    stage(Ab, 0, 1, t1);
    QK_SYNC(); PV_MMA(AfA, BfB, 0, 2); QK_END();
    // ph3
    PV_LDA(A0, AfB, 2);
    if (nlast) stage(Bb, 1, 0, t2);
    QK_SYNC(); PV_MMA(AfB, BfA, 2, 0); QK_END();
    // ph4 + counted vmcnt covering T1
    if (nlast) stage(Bb, 1, 1, t2);
    QK_SYNC(); PV_MMA(AfB, BfB, 2, 2);
    __builtin_amdgcn_s_setprio(0);
    if (nlast) { asm volatile("s_waitcnt vmcnt(4)" ::: "memory"); }
    else       { asm volatile("s_waitcnt vmcnt(0)" ::: "memory"); }
    __builtin_amdgcn_sched_barrier(0);
    __builtin_amdgcn_s_barrier();
    // ph5
    PV_LDA(A1, AfA, 0); PV_LDB(B1, BfA, 0);
    if (nlast) stage(Ab, 0, 0, t2);
    QK_SYNC(); PV_MMA(AfA, BfA, 0, 0); QK_END();
    // ph6
    PV_LDB(B1, BfB, 2);
    if (nlast) stage(Ab, 0, 1, t2);
    QK_SYNC(); PV_MMA(AfA, BfB, 0, 2); QK_END();
    // ph7
    PV_LDA(A1, AfB, 2);
    if (nlast) stage(Bb, 1, 0, t3);
    QK_SYNC(); PV_MMA(AfB, BfA, 2, 0); QK_END();
    // ph8 + counted vmcnt covering next T0
    if (nlast) stage(Bb, 1, 1, t3);
    QK_SYNC(); PV_MMA(AfB, BfB, 2, 2);
    __builtin_amdgcn_s_setprio(0);
    if (nlast) { asm volatile("s_waitcnt vmcnt(4)" ::: "memory"); }
    __builtin_amdgcn_sched_barrier(0);
    __builtin_amdgcn_s_barrier();
  }

  // epilogue: coalesced restage (stride 144 shorts -> quad-disjoint banks)
  unsigned short* sm16 = (unsigned short*)lds;
  __syncthreads();
#pragma unroll
  for (int fi = 0; fi < 4; ++fi)
#pragma unroll
    for (int fj = 0; fj < 4; ++fj) {
      int lcol = wn * 64 + fj * 16 + ln15;
#pragma unroll
      for (int r = 0; r < 4; ++r) {
        int lrow = wm * 64 + fi * 16 + quad * 4 + r;
        sm16[lrow * 144 + lcol] = f2bf(acc[fi][fj][r]);
      }
    }
  __syncthreads();
#pragma unroll
  for (int u = 0; u < 8; ++u) {
    int s = (t + u * 256) * 8;
    int lr = s >> 7, lc = s & 127;
    uint4 d = *(const uint4*)(sm16 + lr * 144 + lc);
    *(uint4*)(Oz + (size_t)(m0 + lr) * CC + n0 + lc) = d;
  }
}

// ---------------------------------------------------------------------------
// Generic TN bf16 MFMA GEMM (R4 form): 2-phase dbuf prefetch, NC K-chunks,
// optional XCD swizzle. CSTG: coalesced bf16 epilogue (stride BN+16).
// ---------------------------------------------------------------------------
template <int BM, int BN, int NC, int WM, int WN, int WX, int BIAS, bool RESID,
          bool OUTF32, bool CSTG, bool SWZ>
__global__ __launch_bounds__(256) void gemm_tn(
    const unsigned short* __restrict__ A, int lda, size_t sA,
    const unsigned short* __restrict__ B, int ldb, size_t sB,
    void* __restrict__ Cout, int ldc, size_t sC, const float* __restrict__ bias,
    const float* __restrict__ resid, size_t sR, int K, float scale) {
  constexpr int HALF = NC * (BM + BN) * 32;
  constexpr int RPP = (BM < 64) ? BM : 64;
  constexpr int LDW = BN + 16;
  constexpr int CSTG_SH = CSTG ? RPP * LDW : 0;
  constexpr int SMEMN = (2 * HALF > CSTG_SH) ? 2 * HALF : CSTG_SH;
  __shared__ __align__(16) unsigned short smem[SMEMN];

  int bx = blockIdx.x, by = blockIdx.y, bz = blockIdx.z;
  if (SWZ) {
    const int gx = gridDim.x, gy = gridDim.y;
    const int n = gx * gy * gridDim.z;
    int f = (bz * gy + by) * gx + bx;
    int w = (f & 7) * (n >> 3) + (f >> 3);
    bx = w % gx; int rem = w / gx; by = rem % gy; bz = rem / gy;
  }

  A += (size_t)bz * sA;
  B += (size_t)bz * sB;
  unsigned short* Cb = (unsigned short*)Cout + (size_t)bz * sC;
  float* Cf = (float*)Cout + (size_t)bz * sC;
  if (RESID) resid += (size_t)bz * sR;
  const int m0 = by * BM;
  const int n0 = bx * BN;
  const int t = threadIdx.x;
  const int wave = t >> 6, lane = t & 63;
  const int ln15 = lane & 15, quad = lane >> 4;
  const int wm0 = (wave / WX) * (WM * 16);
  const int wn0 = (wave % WX) * (WN * 16);
  const int srow = lane >> 2;
  const int scol = (lane & 3) * 8;

  const unsigned short* Ag = A + (size_t)(m0 + srow) * lda + scol;
  const unsigned short* Bg = B + (size_t)(n0 + srow) * ldb + scol;

  f32x4 acc[WM][WN];
#pragma unroll
  for (int i = 0; i < WM; ++i)
#pragma unroll
    for (int j = 0; j < WN; ++j) {
      acc[i][j][0] = 0.f; acc[i][j][1] = 0.f;
      acc[i][j][2] = 0.f; acc[i][j][3] = 0.f;
    }

  auto stage = [&](int buf, int k0) {
    unsigned short* Ab = smem + buf * HALF;
    unsigned short* Bb = Ab + NC * BM * 32;
#pragma unroll
    for (int c = 0; c < NC; ++c) {
#pragma unroll
      for (int r = wave; r < BM / 16; r += 4)
        GLOAD16(Ag + (size_t)(r * 16) * lda + k0 + c * 32,
                Ab + (c * BM + r * 16) * 32);
#pragma unroll
      for (int r = wave; r < BN / 16; r += 4)
        GLOAD16(Bg + (size_t)(r * 16) * ldb + k0 + c * 32,
                Bb + (c * BN + r * 16) * 32);
    }
  };

  const int nt = K / (NC * 32);
  stage(0, 0);
  __syncthreads();
  for (int it = 0; it < nt; ++it) {
    const int cur = it & 1;
    if (it + 1 < nt) stage(cur ^ 1, (it + 1) * NC * 32);
    const unsigned short* Ab = smem + cur * HALF;
    const unsigned short* Bb = Ab + NC * BM * 32;
#pragma unroll
    for (int c = 0; c < NC; ++c) {
      bf16x8 af[WM], bfr[WN];
#pragma unroll
      for (int i = 0; i < WM; ++i)
        af[i] = *(const bf16x8*)(Ab + (c * BM + wm0 + i * 16 + ln15) * 32 +
                                 quad * 8);
#pragma unroll
      for (int j = 0; j < WN; ++j)
        bfr[j] = *(const bf16x8*)(Bb + (c * BN + wn0 + j * 16 + ln15) * 32 +
                                  quad * 8);
#pragma unroll
      for (int i = 0; i < WM; ++i)
#pragma unroll
        for (int j = 0; j < WN; ++j)
          acc[i][j] = __builtin_amdgcn_mfma_f32_16x16x32_bf16(af[i], bfr[j],
                                                              acc[i][j], 0, 0, 0);
    }
    __syncthreads();
  }

  if (CSTG) {
#pragma unroll
    for (int h = 0; h < BM / RPP; ++h) {
      if (wm0 / RPP == h) {
#pragma unroll
        for (int i = 0; i < WM; ++i)
#pragma unroll
          for (int j = 0; j < WN; ++j) {
            int lcol = wn0 + j * 16 + ln15;
#pragma unroll
            for (int r = 0; r < 4; ++r) {
              int lrow = (wm0 % RPP) + i * 16 + quad * 4 + r;
              smem[lrow * LDW + lcol] = f2bf(acc[i][j][r] * scale);
            }
          }
      }
      __syncthreads();
#pragma unroll
      for (int u = 0; u < RPP * BN / 8 / 256; ++u) {
        int s = (t + u * 256) * 8;
        int lr = s / BN, lc = s % BN;
        uint4 d = *(const uint4*)(smem + lr * LDW + lc);
        *(uint4*)(Cb + (size_t)(m0 + h * RPP + lr) * ldc + n0 + lc) = d;
      }
      __syncthreads();
    }
    return;
  }

#pragma unroll
  for (int i = 0; i < WM; ++i) {
#pragma unroll
    for (int j = 0; j < WN; ++j) {
      int col = n0 + wn0 + j * 16 + ln15;
      float bcol = (BIAS == 2) ? bias[col] : 0.f;
#pragma unroll
      for (int r = 0; r < 4; ++r) {
        int row = m0 + wm0 + i * 16 + quad * 4 + r;
        float v = acc[i][j][r] * scale;
        if (BIAS == 1) v += bias[row];
        if (BIAS == 2) v += bcol;
        if (RESID) v += resid[(size_t)row * ldc + col];
        if (OUTF32)
          Cf[(size_t)row * ldc + col] = v;
        else
          Cb[(size_t)row * ldc + col] = f2bf(v);
      }
    }
  }
}

// ---------------------------------------------------------------------------
// In-place bf16 row softmax (fp32 math)
// ---------------------------------------------------------------------------
__global__ __launch_bounds__(256) void softmax_bf16(unsigned short* __restrict__ S) {
  int i = blockIdx.x;
  uint4* row4 = (uint4*)(S + (size_t)i * NN);
  int t = threadIdx.x;
  uint4 d[2];
  d[0] = row4[t];
  d[1] = row4[t + 256];
  float f[16];
#pragma unroll
  for (int h = 0; h < 2; ++h) {
    unsigned w[4] = {d[h].x, d[h].y, d[h].z, d[h].w};
#pragma unroll
    for (int q = 0; q < 4; ++q) {
      union { unsigned u; float f; } lo, hi;
      lo.u = w[q] << 16;
      hi.u = w[q] & 0xFFFF0000u;
      f[h * 8 + 2 * q] = lo.f;
      f[h * 8 + 2 * q + 1] = hi.f;
    }
  }
  float m = -1e30f;
#pragma unroll
  for (int e = 0; e < 16; ++e) m = fmaxf(m, f[e]);
  __shared__ float red[256];
  red[t] = m;
  __syncthreads();
  for (int o = 128; o > 0; o >>= 1) {
    if (t < o) red[t] = fmaxf(red[t], red[t + o]);
    __syncthreads();
  }
  m = red[0];
  __syncthreads();
  float s = 0.f;
#pragma unroll
  for (int e = 0; e < 16; ++e) {
    f[e] = __expf(f[e] - m);
    s += f[e];
  }
  red[t] = s;
  __syncthreads();
  for (int o = 128; o > 0; o >>= 1) {
    if (t < o) red[t] += red[t + o];
    __syncthreads();
  }
  float inv = 1.0f / red[0];
#pragma unroll
  for (int h = 0; h < 2; ++h) {
    unsigned w[4];
#pragma unroll
    for (int q = 0; q < 4; ++q) {
      unsigned short b0 = f2bf(f[h * 8 + 2 * q] * inv);
      unsigned short b1 = f2bf(f[h * 8 + 2 * q + 1] * inv);
      w[q] = ((unsigned)b1 << 16) | (unsigned)b0;
    }
    uint4 o4; o4.x = w[0]; o4.y = w[1]; o4.z = w[2]; o4.w = w[3];
    row4[t + h * 256] = o4;
  }
}

// ---------------------------------------------------------------------------
extern "C" void kernel_launch(void* const* d_in, const int* in_sizes, int n_in,
                              void* d_out, int out_size, void* d_ws,
                              size_t ws_size, hipStream_t stream) {
  const float* x = (const float*)d_in[0];
  const float* gamma = (const float*)d_in[1];
  const float* beta = (const float*)d_in[2];
  const float* Wq = (const float*)d_in[3];
  const float* bq = (const float*)d_in[4];
  const float* Wk = (const float*)d_in[5];
  const float* bk = (const float*)d_in[6];
  const float* Wv = (const float*)d_in[7];
  const float* bv = (const float*)d_in[8];
  const float* Wp = (const float*)d_in[9];
  const float* bp = (const float*)d_in[10];
  float* out = (float*)d_out;

  char* p = (char*)d_ws;
  const size_t CN = (size_t)NN * CC;
  const size_t CNB = CN * 2;
  unsigned short* qt = (unsigned short*)p; p += 2 * CNB;
  unsigned short* kt = (unsigned short*)p; p += 2 * CNB;
  unsigned short* vv = (unsigned short*)p; p += 2 * CNB;
  unsigned short* S  = (unsigned short*)p; p += (size_t)2 * NN * NN * 2;
  unsigned short* w16 = (unsigned short*)p; p += (size_t)4 * CC * CC * 2;
  unsigned short* wq16 = w16;
  unsigned short* wk16 = w16 + (size_t)CC * CC;
  unsigned short* wv16 = w16 + (size_t)2 * CC * CC;
  unsigned short* wp16 = w16 + (size_t)3 * CC * CC;
  float* scale = (float*)p; p += BB * CC * 4;
  float* shift = (float*)p;
  unsigned short* ht = S;   // alias: ht pair lives in S head until QK runs
  unsigned short* ot = qt;  // alias: qt dead after QK, ot born at PV

  const float rs = 0.04419417382415922f;  // 1/sqrt(512)

  gn_stats<<<BB * GG, 1024, 0, stream>>>(x, gamma, beta, scale, shift);
  cvt_bf16_all<<<dim3(256, 4), 256, 0, stream>>>(Wq, Wk, Wv, Wp, wq16, wk16,
                                                 wv16, wp16);

  for (int pr = 0; pr < BB / 2; ++pr) {
    const int b0 = pr * 2;
    gn_apply_t<<<dim3(NN / 64, CC / 64, 2), 256, 0, stream>>>(
        x + (size_t)b0 * CN, scale + b0 * CC, shift + b0 * CC, ht);
    qkv_conv<<<dim3(CC / 64, NN / 128, 2), 256, 0, stream>>>(
        ht, wq16, wk16, wv16, bq, bk, bv, qt, kt, vv);
    // S[z] = (qt[z] . kt[z]^T) * rs  -- 8-phase 256^2 kernel
    qk8<<<dim3(NN / 256, NN / 256, 2), 512, 0, stream>>>(qt, kt, S, rs);
    softmax_bf16<<<2 * NN, 256, 0, stream>>>(S);
    // PV: 8-phase 128^2 kernel, full-K (4096), wave tile 64x64
    pv8<<<dim3(CC / 128, NN / 128, 2), 256, 0, stream>>>(S, vv, ot);
    // proj + bias + residual, fp32 out, BK=64, prefetch + swizzle
    gemm_tn<64, 64, 2, 2, 2, 2, 1, true, true, false, true>
        <<<dim3(NN / 64, CC / 64, 2), 256, 0, stream>>>(
            wp16, CC, 0, ot, CC, CN, out + (size_t)b0 * CN, NN, CN, bp,
            x + (size_t)b0 * CN, CN, CC, 1.0f);
  }
}